// Round 5
// baseline (276.013 us; speedup 1.0000x reference)
//
#include <hip/hip_runtime.h>

// Problem constants
#define B_ 4
#define L_ 2048
#define E_ 1024
#define H_ 16
#define D_ 64
// scale = 1/sqrt(E) = 1/32; folded with log2(e) for exp2-based softmax.
// Baked into K in the GEMM-QK epilogue.
#define CSCALE 0.045084960222629414f

typedef short s16x8 __attribute__((ext_vector_type(8)));
typedef short s16x4 __attribute__((ext_vector_type(4)));
typedef float f32x4 __attribute__((ext_vector_type(4)));
typedef float f32x16 __attribute__((ext_vector_type(16)));
typedef unsigned int u32;

__device__ __forceinline__ unsigned short f2bf(float f) {
  union { float f; unsigned int u; } v;
  v.f = f;
  unsigned int u = v.u;
  u += 0x7fffu + ((u >> 16) & 1u);   // round-to-nearest-even
  return (unsigned short)(u >> 16);
}

// async global->LDS, 16B per lane; HW dest = wave-uniform base + lane*16
__device__ __forceinline__ void async16(const void* g, void* l) {
  __builtin_amdgcn_global_load_lds(
      (__attribute__((address_space(1))) void*)(g),
      (__attribute__((address_space(3))) void*)(l), 16, 0, 0);
}

// ---------------- prep (fused): x fp32->bf16  +  4x W transpose ----------------
__global__ void k_prep(const float* __restrict__ x,
                       const float* __restrict__ Wq, const float* __restrict__ Wk,
                       const float* __restrict__ Wv, const float* __restrict__ Wo,
                       unsigned short* __restrict__ xb,
                       unsigned short* __restrict__ Wt, unsigned short* __restrict__ WoT) {
  __shared__ float t[32][33];
  int bid = blockIdx.x, tid = threadIdx.x;
  if (bid < 8192) {
    int i = bid * 256 + tid;
    float4 v = ((const float4*)x)[i];
    ushort4 o;
    o.x = f2bf(v.x); o.y = f2bf(v.y); o.z = f2bf(v.z); o.w = f2bf(v.w);
    ((ushort4*)xb)[i] = o;
    return;
  }
  int tt = bid - 8192;
  int wsel = tt >> 10, tile = tt & 1023;
  const float* in = (wsel == 0) ? Wq : (wsel == 1) ? Wk : (wsel == 2) ? Wv : Wo;
  unsigned short* out = (wsel == 0) ? Wt : (wsel == 1) ? Wt + (1u << 20)
                        : (wsel == 2) ? Wt + (2u << 20) : WoT;
  int bx = tile & 31, by = tile >> 5;
  int tx = tid & 31, ty = tid >> 5;   // 32 x 8
  int xcol = bx * 32 + tx;
  int y0 = by * 32;
#pragma unroll
  for (int i = 0; i < 4; ++i)
    t[ty + i * 8][tx] = in[(size_t)(y0 + ty + i * 8) * 1024 + xcol];
  __syncthreads();
  int xo = by * 32 + tx;
  int yo0 = bx * 32;
#pragma unroll
  for (int i = 0; i < 4; ++i)
    out[(size_t)(yo0 + ty + i * 8) * 1024 + xo] = f2bf(t[tx][ty + i * 8]);
}

// ---------------- merged GEMM: QK + VT (3-stage counted-vmcnt pipeline) --------
__global__ __launch_bounds__(256) void k_gemm_qkvt(
    const unsigned short* __restrict__ xb, const unsigned short* __restrict__ Wt,
    unsigned short* __restrict__ Qb, unsigned short* __restrict__ Kb,
    unsigned short* __restrict__ Vt) {
  __shared__ __align__(16) unsigned short St[3][2][4096];  // [stage][A|B][128*32]
  const int bid = blockIdx.x;
  const int tid = threadIdx.x;
  const int w = tid >> 6, lane = tid & 63;
  const int quad = lane >> 4, mrow = lane & 15;
  const bool isQK = bid < 1024;
  int m0, n0;
  const unsigned short *PA, *PB;
  if (isQK) {
    m0 = (bid & 63) * 128;           // token
    n0 = (bid >> 6) * 128;           // feature in [0,2048)
    PA = xb + (size_t)m0 * 1024;
    PB = Wt + (size_t)n0 * 1024;
  } else {
    int g = bid - 1024;
    m0 = (g & 7) * 128;              // feature (h*64+d)
    n0 = (g >> 3) * 128;             // token
    PA = Wt + (2u << 20) + (size_t)m0 * 1024;   // WvT
    PB = xb + (size_t)n0 * 1024;
  }
  const int wr = (w >> 1) * 64, wc = (w & 1) * 64;

  // stage issue: 4 async16/thread (A 2 + B 2)
  auto issue = [&](int kt, int s) {
    int ktw = kt & 31;   // wrap past the end: junk prefetch, keeps vmcnt uniform
#pragma unroll
    for (int r = 0; r < 2; ++r) {
      int c = r * 256 + tid;           // 512 chunks of 8 bf16 per array
      int row = c >> 2, cc = c & 3;
      async16(PA + (size_t)row * 1024 + ktw * 32 + cc * 8, &St[s][0][c * 8]);
      async16(PB + (size_t)row * 1024 + ktw * 32 + cc * 8, &St[s][1][c * 8]);
    }
  };

  const f32x4 fz = {0.f, 0.f, 0.f, 0.f};
  f32x4 acc[4][4];
#pragma unroll
  for (int a = 0; a < 4; ++a)
#pragma unroll
    for (int b = 0; b < 4; ++b) acc[a][b] = fz;

  // prologue: fill stages 0,1
  issue(0, 0);
  issue(1, 1);

  for (int kt = 0; kt < 32; ++kt) {
    asm volatile("s_waitcnt vmcnt(4)" ::: "memory");
    __builtin_amdgcn_s_barrier();
    asm volatile("" ::: "memory");
    issue(kt + 2, (kt + 2) % 3);
    const unsigned short* As = &St[kt % 3][0][0];
    const unsigned short* Bs = &St[kt % 3][1][0];
    s16x8 a[4], b[4];
#pragma unroll
    for (int mt = 0; mt < 4; ++mt)
      a[mt] = *(const s16x8*)&As[(wr + mt * 16 + mrow) * 32 + quad * 8];
#pragma unroll
    for (int nt = 0; nt < 4; ++nt)
      b[nt] = *(const s16x8*)&Bs[(wc + nt * 16 + mrow) * 32 + quad * 8];
#pragma unroll
    for (int mt = 0; mt < 4; ++mt)
#pragma unroll
      for (int nt = 0; nt < 4; ++nt)
        acc[mt][nt] = __builtin_amdgcn_mfma_f32_16x16x32_bf16(a[mt], b[nt], acc[mt][nt], 0, 0, 0);
  }
  // epilogue: C/D layout col=lane&15, row=quad*4+i
  if (isQK) {
#pragma unroll
    for (int mt = 0; mt < 4; ++mt)
#pragma unroll
      for (int nt = 0; nt < 4; ++nt)
#pragma unroll
        for (int i = 0; i < 4; ++i) {
          int row = m0 + wr + mt * 16 + quad * 4 + i;   // token
          int col = n0 + wc + nt * 16 + mrow;           // feature
          int bb = row >> 11, l = row & 2047;
          if (col < 1024) {
            int h = col >> 6, d = col & 63;
            Qb[(((size_t)(bb * 16 + h)) * 2048 + l) * 64 + d] = f2bf(acc[mt][nt][i]);
          } else {
            int c2 = col - 1024, h = c2 >> 6, d = c2 & 63;
            Kb[(((size_t)(bb * 16 + h)) * 2048 + l) * 64 + d] = f2bf(acc[mt][nt][i] * CSCALE);
          }
        }
  } else {
#pragma unroll
    for (int mt = 0; mt < 4; ++mt)
#pragma unroll
      for (int nt = 0; nt < 4; ++nt)
#pragma unroll
        for (int i = 0; i < 4; ++i) {
          int f = m0 + wr + mt * 16 + quad * 4 + i;     // feature
          int tk = n0 + wc + nt * 16 + mrow;            // token
          int bb = tk >> 11, l = tk & 2047;
          Vt[((size_t)(bb * 1024 + f)) * 2048 + l] = f2bf(acc[mt][nt][i]);
        }
  }
}

// ---------------- flash attention: 32x32 MFMA + in-register repack ------------
// Rounds 0-4: MfmaUtil+VALUBusy pinned ~92% at any occupancy -> three pipes
// (matrix 233cyc, LDS 208cyc, VALU) each ~45-50us, ~50% overlapped. Fix = less
// per-pipe work, not scheduling:
//  * QK^T and PV both as mfma_f32_32x32x16_bf16 (full rate). PV was 32x
//    half-rate 16x16x16 -> now 8x full-rate: PV matrix cycles halved.
//  * S^T C-layout (verified m74/m101): col=q=lane&31, row=l=(r&3)+8(r>>2)+4hi.
//    PV A-frag needs (m=q=lane&31, k=hi*8+j). Derivation: target k-octet =
//    own regs (2cc+hi)*4..+3  +  lane^32's same regs -> cvt_pk pairs + one
//    __shfl_xor(32) per u32-pair (T12 recipe).
//  * row-sums via ones-column MFMA: o_sum += mfma(pa, ones) -- kills 32 VALU
//    adds/iter and the epilogue shuffle-reduce; o_sum C rows match o exactly.
// MFMA issues 48->20, ds_reads 24->16 (all b128), matrix cyc -31%.
__device__ __forceinline__ u32 pkbf(float a, float b) {
  u32 r;
  asm("v_cvt_pk_bf16_f32 %0, %1, %2" : "=v"(r) : "v"(a), "v"(b));
  return r;
}

// s (16 f32, S^T tile) -> two PV A-frag chunks (l = cc*16 + hi*8 + j)
__device__ __forceinline__ void exp_repack(const f32x16 s, int hi,
                                           s16x8& paLo, s16x8& paHi) {
  float p[16];
#pragma unroll
  for (int r = 0; r < 16; ++r) p[r] = __builtin_amdgcn_exp2f(s[r]);
  u32 u[8];
#pragma unroll
  for (int t = 0; t < 8; ++t) u[t] = pkbf(p[2 * t], p[2 * t + 1]);
#pragma unroll
  for (int cc = 0; cc < 2; ++cc) {
    u32 X0 = hi ? u[cc * 4 + 2] : u[cc * 4 + 0];
    u32 X1 = hi ? u[cc * 4 + 3] : u[cc * 4 + 1];
    u32 Y0 = hi ? u[cc * 4 + 0] : u[cc * 4 + 2];
    u32 Y1 = hi ? u[cc * 4 + 1] : u[cc * 4 + 3];
    u32 Z0 = (u32)__shfl_xor((int)Y0, 32, 64);
    u32 Z1 = (u32)__shfl_xor((int)Y1, 32, 64);
    union { u32 w[4]; s16x8 v; } f;
    f.w[0] = hi ? Z0 : X0;
    f.w[1] = hi ? Z1 : X1;
    f.w[2] = hi ? X0 : Z0;
    f.w[3] = hi ? X1 : Z1;
    if (cc == 0) paLo = f.v; else paHi = f.v;
  }
}

__global__ __launch_bounds__(512) void k_attn(
    const unsigned short* __restrict__ Qb, const unsigned short* __restrict__ Kb,
    const unsigned short* __restrict__ Vt, unsigned short* __restrict__ AO) {
  __shared__ __align__(16) unsigned short KVs[4][8192];  // per buf: [K 8KB | V 8KB]
  const int tid = threadIdx.x, w = tid >> 6, lane = tid & 63;
  const int lo5 = lane & 31, hi = lane >> 5;
  const int bh = blockIdx.y;
  const int q0 = blockIdx.x * 256;
  const unsigned short* Qh = Qb + (size_t)bh * 2048 * 64;
  const unsigned short* Kh = Kb + (size_t)bh * 2048 * 64;
  const unsigned short* Vh = Vt + (size_t)bh * 64 * 2048;
  unsigned short* KVf = &KVs[0][0];

  // stage Q tile [256][64] through bufs 0-1 (32KB), swizzled
#pragma unroll
  for (int r = 0; r < 4; ++r) {
    int c = r * 512 + tid;       // 2048 chunks
    int row = c >> 3, cl = c & 7;
    int gc = cl ^ (row & 7);
    async16(Qh + (size_t)(q0 + row) * 64 + gc * 8, &KVf[c * 8]);
  }
  asm volatile("s_waitcnt vmcnt(0)" ::: "memory");
  __builtin_amdgcn_s_barrier();
  asm volatile("" ::: "memory");
  // Q B-frags (persist): B[n=q=lane&31][k=hi*8+j], chunk c -> d=c*16+hi*8
  s16x8 qb[4];
  {
    int row = w * 32 + lo5, sw = row & 7;
#pragma unroll
    for (int c = 0; c < 4; ++c)
      qb[c] = *(const s16x8*)&KVf[row * 64 + (((2 * c + hi) ^ sw) << 3)];
  }
  asm volatile("" ::: "memory");
  __builtin_amdgcn_s_barrier();   // all waves done reading Q; bufs 0-1 free
  asm volatile("" ::: "memory");

  // prologue: issue j=0 -> buf0, j=1 -> buf1 (2 async16/thread each)
  {
    int row = tid >> 3, cl = tid & 7, gc = cl ^ (row & 7);
    async16(Kh + (size_t)row * 64 + gc * 8, &KVs[0][tid * 8]);
    async16(Vh + (size_t)row * 2048 + gc * 8, &KVs[0][4096 + tid * 8]);
    async16(Kh + (size_t)(64 + row) * 64 + gc * 8, &KVs[1][tid * 8]);
    async16(Vh + (size_t)row * 2048 + 64 + gc * 8, &KVs[1][4096 + tid * 8]);
  }

  f32x16 o0, o1, osum;
#pragma unroll
  for (int i = 0; i < 16; ++i) { o0[i] = 0.f; o1[i] = 0.f; osum[i] = 0.f; }
  const s16x8 ones = {0x3F80, 0x3F80, 0x3F80, 0x3F80, 0x3F80, 0x3F80, 0x3F80, 0x3F80};

  for (int j = 0; j < 32; ++j) {
    // issue prefetch j+2 into buf (j+2)&3 (wrap past end: harmless junk)
    {
      int jj = (j + 2) & 31;
      unsigned short* nb = &KVs[(j + 2) & 3][0];
      int row = tid >> 3, cl = tid & 7, gc = cl ^ (row & 7);
      async16(Kh + (size_t)(jj * 64 + row) * 64 + gc * 8, &nb[tid * 8]);
      async16(Vh + (size_t)row * 2048 + jj * 64 + gc * 8, &nb[4096 + tid * 8]);
    }
    // counted wait: 4 outstanding = loads(j+1)+loads(j+2); never 0 in loop (T4)
    asm volatile("s_waitcnt vmcnt(4)" ::: "memory");
    __builtin_amdgcn_s_barrier();
    asm volatile("" ::: "memory");
    const unsigned short* Kt = &KVs[j & 3][0];
    const unsigned short* Vs = &KVs[j & 3][4096];

    // K A-frags: tile mt: A[m=l=mt*32+lane&31][k=hi*8+j], chunk c -> d=c*16+hi*8
    s16x8 ak0[4], ak1[4], vb0[4], vb1[4];
    {
      int r0 = lo5, s0w = r0 & 7, r1 = 32 + lo5, s1w = r1 & 7;
#pragma unroll
      for (int c = 0; c < 4; ++c) {
        ak0[c] = *(const s16x8*)&Kt[r0 * 64 + (((2 * c + hi) ^ s0w) << 3)];
        ak1[c] = *(const s16x8*)&Kt[r1 * 64 + (((2 * c + hi) ^ s1w) << 3)];
        // V B-frags: B[n=d=ntd*32+lane&31][k=hi*8+j], chunk c -> l=c*16+hi*8
        vb0[c] = *(const s16x8*)&Vs[r0 * 64 + (((2 * c + hi) ^ s0w) << 3)];
        vb1[c] = *(const s16x8*)&Vs[r1 * 64 + (((2 * c + hi) ^ s1w) << 3)];
      }
    }

    // S^T = K Q^T : two 32x32 tiles (l 0-31, 32-63) x (q = w*32 + 0-31)
    f32x16 s0, s1;
#pragma unroll
    for (int i = 0; i < 16; ++i) { s0[i] = 0.f; s1[i] = 0.f; }
    __builtin_amdgcn_s_setprio(1);
#pragma unroll
    for (int c = 0; c < 4; ++c) {
      s0 = __builtin_amdgcn_mfma_f32_32x32x16_bf16(ak0[c], qb[c], s0, 0, 0, 0);
      s1 = __builtin_amdgcn_mfma_f32_32x32x16_bf16(ak1[c], qb[c], s1, 0, 0, 0);
    }
    __builtin_amdgcn_s_setprio(0);

    // softmax-lite: exp2 + pack into PV A-frags (cvt_pk + shfl_xor(32))
    s16x8 pa[4];
    exp_repack(s0, hi, pa[0], pa[1]);
    exp_repack(s1, hi, pa[2], pa[3]);

    // O += P V  and  o_sum += P 1 (ones-column row sums, free layout match)
    __builtin_amdgcn_s_setprio(1);
#pragma unroll
    for (int c = 0; c < 4; ++c) {
      o0 = __builtin_amdgcn_mfma_f32_32x32x16_bf16(pa[c], vb0[c], o0, 0, 0, 0);
      o1 = __builtin_amdgcn_mfma_f32_32x32x16_bf16(pa[c], vb1[c], o1, 0, 0, 0);
      osum = __builtin_amdgcn_mfma_f32_32x32x16_bf16(pa[c], ones, osum, 0, 0, 0);
    }
    __builtin_amdgcn_s_setprio(0);
  }

  // normalize + write AO [B][L][H*D] bf16
  // C layout 32x32: row q = (i&3)+8*(i>>2)+4*hi, col d = ntd*32 + lane&31
  int b_ = bh >> 4, h = bh & 15;
#pragma unroll
  for (int i = 0; i < 16; ++i) {
    float inv = 1.f / osum[i];
    int qrow = q0 + w * 32 + (i & 3) + 8 * (i >> 2) + 4 * hi;
    size_t base = ((size_t)(b_ * 2048 + qrow)) * 1024 + h * 64 + lo5;
    AO[base] = f2bf(o0[i] * inv);
    AO[base + 32] = f2bf(o1[i] * inv);
  }
}

// ---------------- GEMM2: out = AO @ WoT^T + bo (3-stage counted-vmcnt) --------
__global__ __launch_bounds__(256) void k_gemm_out(
    const unsigned short* __restrict__ Ab, const unsigned short* __restrict__ WoT,
    const float* __restrict__ bo, float* __restrict__ out) {
  __shared__ __align__(16) unsigned short St[3][2][4096];
  const int tid = threadIdx.x;
  const int w = tid >> 6, lane = tid & 63;
  const int quad = lane >> 4, mrow = lane & 15;
  const int m0 = blockIdx.x * 128, n0 = blockIdx.y * 128;
  const int wr = (w >> 1) * 64, wc = (w & 1) * 64;
  const unsigned short* PA = Ab + (size_t)m0 * 1024;
  const unsigned short* PB = WoT + (size_t)n0 * 1024;

  auto issue = [&](int kt, int s) {
    int ktw = kt & 31;
#pragma unroll
    for (int r = 0; r < 2; ++r) {
      int c = r * 256 + tid;
      int row = c >> 2, cc = c & 3;
      async16(PA + (size_t)row * 1024 + ktw * 32 + cc * 8, &St[s][0][c * 8]);
      async16(PB + (size_t)row * 1024 + ktw * 32 + cc * 8, &St[s][1][c * 8]);
    }
  };

  const f32x4 fz = {0.f, 0.f, 0.f, 0.f};
  f32x4 acc[4][4];
#pragma unroll
  for (int a = 0; a < 4; ++a)
#pragma unroll
    for (int b = 0; b < 4; ++b) acc[a][b] = fz;

  issue(0, 0);
  issue(1, 1);

  for (int kt = 0; kt < 32; ++kt) {
    asm volatile("s_waitcnt vmcnt(4)" ::: "memory");
    __builtin_amdgcn_s_barrier();
    asm volatile("" ::: "memory");
    issue(kt + 2, (kt + 2) % 3);
    const unsigned short* As = &St[kt % 3][0][0];
    const unsigned short* Bs = &St[kt % 3][1][0];
    s16x8 a[4], b[4];
#pragma unroll
    for (int mt = 0; mt < 4; ++mt)
      a[mt] = *(const s16x8*)&As[(wr + mt * 16 + mrow) * 32 + quad * 8];
#pragma unroll
    for (int nt = 0; nt < 4; ++nt)
      b[nt] = *(const s16x8*)&Bs[(wc + nt * 16 + mrow) * 32 + quad * 8];
#pragma unroll
    for (int mt = 0; mt < 4; ++mt)
#pragma unroll
      for (int nt = 0; nt < 4; ++nt)
        acc[mt][nt] = __builtin_amdgcn_mfma_f32_16x16x32_bf16(a[mt], b[nt], acc[mt][nt], 0, 0, 0);
  }
#pragma unroll
  for (int mt = 0; mt < 4; ++mt)
#pragma unroll
    for (int nt = 0; nt < 4; ++nt)
#pragma unroll
      for (int i = 0; i < 4; ++i) {
        int row = m0 + wr + mt * 16 + quad * 4 + i;
        int col = n0 + wc + nt * 16 + mrow;
        out[(size_t)row * 1024 + col] = acc[mt][nt][i] + bo[col];
      }
}

extern "C" void kernel_launch(void* const* d_in, const int* in_sizes, int n_in,
                              void* d_out, int out_size, void* d_ws, size_t ws_size,
                              hipStream_t stream) {
  const float* x  = (const float*)d_in[0];
  const float* Wq = (const float*)d_in[1];
  const float* Wk = (const float*)d_in[2];
  const float* Wv = (const float*)d_in[3];
  const float* Wo = (const float*)d_in[4];
  const float* bo = (const float*)d_in[5];
  float* out = (float*)d_out;

  char* ws = (char*)d_ws;
  const size_t MiB = 1u << 20;
  unsigned short* xb  = (unsigned short*)(ws);              // 16 MiB, reused as AO
  unsigned short* Wt  = (unsigned short*)(ws + 16 * MiB);   // 6 MiB  (Wq^T|Wk^T|Wv^T)
  unsigned short* WoT = (unsigned short*)(ws + 22 * MiB);   // 2 MiB
  unsigned short* Qb  = (unsigned short*)(ws + 24 * MiB);   // 16 MiB [B,H,L,D]
  unsigned short* Kb  = (unsigned short*)(ws + 40 * MiB);   // 16 MiB [B,H,L,D] (pre-scaled)
  unsigned short* Vt  = (unsigned short*)(ws + 56 * MiB);   // 16 MiB [B,H,D,L]
  unsigned short* AO  = xb;  // x/xb no longer needed after the merged GEMM

  k_prep<<<12288, 256, 0, stream>>>(x, Wq, Wk, Wv, Wo, xb, Wt, WoT);
  k_gemm_qkvt<<<1536, 256, 0, stream>>>(xb, Wt, Qb, Kb, Vt);
  k_attn<<<dim3(8, 64), 512, 0, stream>>>(Qb, Kb, Vt, AO);
  k_gemm_out<<<dim3(64, 8), 256, 0, stream>>>(AO, WoT, bo, out);
}

// Round 6
// 274.140 us; speedup vs baseline: 1.0068x; 1.0068x over previous
//
#include <hip/hip_runtime.h>

// Problem constants
#define B_ 4
#define L_ 2048
#define E_ 1024
#define H_ 16
#define D_ 64
// scale = 1/sqrt(E) = 1/32; folded with log2(e) for exp2-based softmax.
// Baked into K in the GEMM-QK epilogue.
#define CSCALE 0.045084960222629414f

typedef short s16x8 __attribute__((ext_vector_type(8)));
typedef short s16x4 __attribute__((ext_vector_type(4)));
typedef float f32x4 __attribute__((ext_vector_type(4)));

__device__ __forceinline__ unsigned short f2bf(float f) {
  union { float f; unsigned int u; } v;
  v.f = f;
  unsigned int u = v.u;
  u += 0x7fffu + ((u >> 16) & 1u);   // round-to-nearest-even
  return (unsigned short)(u >> 16);
}

// async global->LDS, 16B per lane; HW dest = wave-uniform base + lane*16
__device__ __forceinline__ void async16(const void* g, void* l) {
  __builtin_amdgcn_global_load_lds(
      (__attribute__((address_space(1))) void*)(g),
      (__attribute__((address_space(3))) void*)(l), 16, 0, 0);
}

// ---------------- prep (fused): x fp32->bf16  +  4x W transpose ----------------
__global__ void k_prep(const float* __restrict__ x,
                       const float* __restrict__ Wq, const float* __restrict__ Wk,
                       const float* __restrict__ Wv, const float* __restrict__ Wo,
                       unsigned short* __restrict__ xb,
                       unsigned short* __restrict__ Wt, unsigned short* __restrict__ WoT) {
  __shared__ float t[32][33];
  int bid = blockIdx.x, tid = threadIdx.x;
  if (bid < 8192) {
    int i = bid * 256 + tid;
    float4 v = ((const float4*)x)[i];
    ushort4 o;
    o.x = f2bf(v.x); o.y = f2bf(v.y); o.z = f2bf(v.z); o.w = f2bf(v.w);
    ((ushort4*)xb)[i] = o;
    return;
  }
  int tt = bid - 8192;
  int wsel = tt >> 10, tile = tt & 1023;
  const float* in = (wsel == 0) ? Wq : (wsel == 1) ? Wk : (wsel == 2) ? Wv : Wo;
  unsigned short* out = (wsel == 0) ? Wt : (wsel == 1) ? Wt + (1u << 20)
                        : (wsel == 2) ? Wt + (2u << 20) : WoT;
  int bx = tile & 31, by = tile >> 5;
  int tx = tid & 31, ty = tid >> 5;   // 32 x 8
  int xcol = bx * 32 + tx;
  int y0 = by * 32;
#pragma unroll
  for (int i = 0; i < 4; ++i)
    t[ty + i * 8][tx] = in[(size_t)(y0 + ty + i * 8) * 1024 + xcol];
  __syncthreads();
  int xo = by * 32 + tx;
  int yo0 = bx * 32;
#pragma unroll
  for (int i = 0; i < 4; ++i)
    out[(size_t)(yo0 + ty + i * 8) * 1024 + xo] = f2bf(t[tx][ty + i * 8]);
}

// ---------------- merged GEMM: QK + VT (3-stage counted-vmcnt pipeline) --------
// + XCD-aware bijective swizzle (T1): 1536 % 8 == 0, swz=(bid&7)*192+(bid>>3).
// Contiguous 192-block chunks per XCD share B panels -> L2 hits.
__global__ __launch_bounds__(256) void k_gemm_qkvt(
    const unsigned short* __restrict__ xb, const unsigned short* __restrict__ Wt,
    unsigned short* __restrict__ Qb, unsigned short* __restrict__ Kb,
    unsigned short* __restrict__ Vt) {
  __shared__ __align__(16) unsigned short St[3][2][4096];  // [stage][A|B][128*32]
  const int bid0 = blockIdx.x;
  const int bid = (bid0 & 7) * 192 + (bid0 >> 3);   // XCD swizzle, bijective
  const int tid = threadIdx.x;
  const int w = tid >> 6, lane = tid & 63;
  const int quad = lane >> 4, mrow = lane & 15;
  const bool isQK = bid < 1024;
  int m0, n0;
  const unsigned short *PA, *PB;
  if (isQK) {
    m0 = (bid & 63) * 128;           // token
    n0 = (bid >> 6) * 128;           // feature in [0,2048)
    PA = xb + (size_t)m0 * 1024;
    PB = Wt + (size_t)n0 * 1024;
  } else {
    int g = bid - 1024;
    m0 = (g & 7) * 128;              // feature (h*64+d)
    n0 = (g >> 3) * 128;             // token
    PA = Wt + (2u << 20) + (size_t)m0 * 1024;   // WvT
    PB = xb + (size_t)n0 * 1024;
  }
  const int wr = (w >> 1) * 64, wc = (w & 1) * 64;

  // stage issue: 4 async16/thread (A 2 + B 2)
  auto issue = [&](int kt, int s) {
    int ktw = kt & 31;   // wrap past the end: junk prefetch, keeps vmcnt uniform
#pragma unroll
    for (int r = 0; r < 2; ++r) {
      int c = r * 256 + tid;           // 512 chunks of 8 bf16 per array
      int row = c >> 2, cc = c & 3;
      async16(PA + (size_t)row * 1024 + ktw * 32 + cc * 8, &St[s][0][c * 8]);
      async16(PB + (size_t)row * 1024 + ktw * 32 + cc * 8, &St[s][1][c * 8]);
    }
  };

  const f32x4 fz = {0.f, 0.f, 0.f, 0.f};
  f32x4 acc[4][4];
#pragma unroll
  for (int a = 0; a < 4; ++a)
#pragma unroll
    for (int b = 0; b < 4; ++b) acc[a][b] = fz;

  // prologue: fill stages 0,1
  issue(0, 0);
  issue(1, 1);

  for (int kt = 0; kt < 32; ++kt) {
    asm volatile("s_waitcnt vmcnt(4)" ::: "memory");
    __builtin_amdgcn_s_barrier();
    asm volatile("" ::: "memory");
    issue(kt + 2, (kt + 2) % 3);
    const unsigned short* As = &St[kt % 3][0][0];
    const unsigned short* Bs = &St[kt % 3][1][0];
    s16x8 a[4], b[4];
#pragma unroll
    for (int mt = 0; mt < 4; ++mt)
      a[mt] = *(const s16x8*)&As[(wr + mt * 16 + mrow) * 32 + quad * 8];
#pragma unroll
    for (int nt = 0; nt < 4; ++nt)
      b[nt] = *(const s16x8*)&Bs[(wc + nt * 16 + mrow) * 32 + quad * 8];
#pragma unroll
    for (int mt = 0; mt < 4; ++mt)
#pragma unroll
      for (int nt = 0; nt < 4; ++nt)
        acc[mt][nt] = __builtin_amdgcn_mfma_f32_16x16x32_bf16(a[mt], b[nt], acc[mt][nt], 0, 0, 0);
  }
  // epilogue: C/D layout col=lane&15, row=quad*4+i
  if (isQK) {
#pragma unroll
    for (int mt = 0; mt < 4; ++mt)
#pragma unroll
      for (int nt = 0; nt < 4; ++nt)
#pragma unroll
        for (int i = 0; i < 4; ++i) {
          int row = m0 + wr + mt * 16 + quad * 4 + i;   // token
          int col = n0 + wc + nt * 16 + mrow;           // feature
          int bb = row >> 11, l = row & 2047;
          if (col < 1024) {
            int h = col >> 6, d = col & 63;
            Qb[(((size_t)(bb * 16 + h)) * 2048 + l) * 64 + d] = f2bf(acc[mt][nt][i]);
          } else {
            int c2 = col - 1024, h = c2 >> 6, d = c2 & 63;
            Kb[(((size_t)(bb * 16 + h)) * 2048 + l) * 64 + d] = f2bf(acc[mt][nt][i] * CSCALE);
          }
        }
  } else {
#pragma unroll
    for (int mt = 0; mt < 4; ++mt)
#pragma unroll
      for (int nt = 0; nt < 4; ++nt)
#pragma unroll
        for (int i = 0; i < 4; ++i) {
          int f = m0 + wr + mt * 16 + quad * 4 + i;     // feature
          int tk = n0 + wc + nt * 16 + mrow;            // token
          int bb = tk >> 11, l = tk & 2047;
          Vt[((size_t)(bb * 1024 + f)) * 2048 + l] = f2bf(acc[mt][nt][i]);
        }
  }
}

// ---------------- flash attention: r4 structure + 3-stage LDS + XCD swizzle ----
// Round-5 lesson: 32x32 MFMA port cut matrix cycles -31% as predicted but the
// longer per-iter dependency chain (4 dep 8cyc MFMAs -> 16-wide exp -> bpermute)
// at 2 blocks/CU raised stalls (busy-sum 92->70). Reverted to r4 16x16 structure.
// New here:
//  (a) 3 LDS stages (48KB, was 64KB) -> 3 blocks/CU (VGPR 56 allows 6 w/SIMD).
//      Loop order {vmcnt(2); barrier; issue(j+2); compute(j)}: the barrier
//      guarantees all waves finished reading buf (j-1)%3 == (j+2)%3 before the
//      overwrite, and vmcnt(2)+barrier guarantees ALL waves' loads(j) landed.
//  (b) XCD swizzle: grid(8,64) had x fastest -> the 8 q-tile blocks of one head
//      spread over 8 XCDs (each XCD streams ~64 heads of K/V). Remap so each
//      XCD owns 8 heads x all 8 q-tiles: per-XCD KV set = 4MB = one L2.
struct AK { s16x8 k0, k1; };
struct ST { f32x4 s0, s1; };
struct PAT { s16x4 n0, n1; };

__device__ __forceinline__ AK load_ak(const unsigned short* Kt, int mt, int mrow, int quad) {
  int row = mt * 16 + mrow;
  AK r;
  r.k0 = *(const s16x8*)&Kt[row * 64 + (((0 + quad) ^ (row & 7)) << 3)];
  r.k1 = *(const s16x8*)&Kt[row * 64 + (((4 + quad) ^ (row & 7)) << 3)];
  return r;
}

__device__ __forceinline__ ST qkmm(const AK& a, const s16x8 (&qb)[2][2]) {
  const f32x4 fz = {0.f, 0.f, 0.f, 0.f};
  ST t; t.s0 = fz; t.s1 = fz;
  __builtin_amdgcn_s_setprio(1);
  t.s0 = __builtin_amdgcn_mfma_f32_16x16x32_bf16(a.k0, qb[0][0], t.s0, 0, 0, 0);
  t.s1 = __builtin_amdgcn_mfma_f32_16x16x32_bf16(a.k0, qb[1][0], t.s1, 0, 0, 0);
  t.s0 = __builtin_amdgcn_mfma_f32_16x16x32_bf16(a.k1, qb[0][1], t.s0, 0, 0, 0);
  t.s1 = __builtin_amdgcn_mfma_f32_16x16x32_bf16(a.k1, qb[1][1], t.s1, 0, 0, 0);
  __builtin_amdgcn_s_setprio(0);
  return t;
}

__device__ __forceinline__ s16x4 exp_pack(const f32x4 sv, float& lracc) {
  float p0 = __builtin_amdgcn_exp2f(sv[0]);
  float p1 = __builtin_amdgcn_exp2f(sv[1]);
  float p2 = __builtin_amdgcn_exp2f(sv[2]);
  float p3 = __builtin_amdgcn_exp2f(sv[3]);
  lracc += (p0 + p1) + (p2 + p3);
  unsigned int r01, r23;
  asm("v_cvt_pk_bf16_f32 %0, %1, %2" : "=v"(r01) : "v"(p0), "v"(p1));
  asm("v_cvt_pk_bf16_f32 %0, %1, %2" : "=v"(r23) : "v"(p2), "v"(p3));
  union { unsigned int u[2]; s16x4 v4; } uu;
  uu.u[0] = r01; uu.u[1] = r23;
  return uu.v4;
}

__device__ __forceinline__ PAT expp(const ST& t, float (&lr)[2]) {
  PAT r;
  r.n0 = exp_pack(t.s0, lr[0]);
  r.n1 = exp_pack(t.s1, lr[1]);
  return r;
}

__device__ __forceinline__ void pv(const unsigned short* Vs, int lt, const PAT& p,
                                   f32x4 (&o)[2][4], int mrow, int quad) {
  s16x4 vb[4];
  int lbase = lt * 16 + quad * 4;
  int cg = lbase >> 3, off = lbase & 7;
#pragma unroll
  for (int dt = 0; dt < 4; ++dt) {
    int row = dt * 16 + mrow;
    vb[dt] = *(const s16x4*)&Vs[row * 64 + ((cg ^ (row & 7)) << 3) + off];
  }
  __builtin_amdgcn_s_setprio(1);
#pragma unroll
  for (int dt = 0; dt < 4; ++dt) {
    o[0][dt] = __builtin_amdgcn_mfma_f32_16x16x16bf16_1k(p.n0, vb[dt], o[0][dt], 0, 0, 0);
    o[1][dt] = __builtin_amdgcn_mfma_f32_16x16x16bf16_1k(p.n1, vb[dt], o[1][dt], 0, 0, 0);
  }
  __builtin_amdgcn_s_setprio(0);
}

__global__ __launch_bounds__(512) void k_attn(
    const unsigned short* __restrict__ Qb, const unsigned short* __restrict__ Kb,
    const unsigned short* __restrict__ Vt, unsigned short* __restrict__ AO) {
  __shared__ __align__(16) unsigned short KVs[3][8192];  // per buf: [K 8KB | V 8KB]
  const int tid = threadIdx.x, w = tid >> 6, lane = tid & 63;
  const int quad = lane >> 4, mrow = lane & 15;
  // XCD swizzle: lin = x + 8*y (x fastest in dispatch); swz chunks 64 blocks/XCD
  const int lin = blockIdx.x + 8 * blockIdx.y;
  const int swz = (lin & 7) * 64 + (lin >> 3);   // 512 % 8 == 0 -> bijective
  const int bh = swz >> 3;
  const int q0 = (swz & 7) * 256;
  const unsigned short* Qh = Qb + (size_t)bh * 2048 * 64;
  const unsigned short* Kh = Kb + (size_t)bh * 2048 * 64;
  const unsigned short* Vh = Vt + (size_t)bh * 64 * 2048;
  unsigned short* KVf = &KVs[0][0];

  // stage Q tile [256][64] through bufs 0-1 (32KB), swizzled
#pragma unroll
  for (int r = 0; r < 4; ++r) {
    int c = r * 512 + tid;       // 2048 chunks
    int row = c >> 3, cl = c & 7;
    int gc = cl ^ (row & 7);
    async16(Qh + (size_t)(q0 + row) * 64 + gc * 8, &KVf[c * 8]);
  }
  asm volatile("s_waitcnt vmcnt(0)" ::: "memory");
  __builtin_amdgcn_s_barrier();
  asm volatile("" ::: "memory");
  // Q B-frags (persist in regs): B[n=q][k=d], q = w*32 + nt*16 + mrow
  s16x8 qb[2][2];
#pragma unroll
  for (int nt = 0; nt < 2; ++nt)
#pragma unroll
    for (int ks = 0; ks < 2; ++ks) {
      int row = w * 32 + nt * 16 + mrow;
      qb[nt][ks] = *(const s16x8*)&KVf[row * 64 + (((ks * 4 + quad) ^ (row & 7)) << 3)];
    }
  asm volatile("" ::: "memory");
  __builtin_amdgcn_s_barrier();   // all waves done reading Q; bufs free
  asm volatile("" ::: "memory");

  // prologue: issue j=0 -> buf0, j=1 -> buf1 (2 async16/thread each)
  {
    int row = tid >> 3, cl = tid & 7, gc = cl ^ (row & 7);
    async16(Kh + (size_t)row * 64 + gc * 8, &KVs[0][tid * 8]);
    async16(Vh + (size_t)row * 2048 + gc * 8, &KVs[0][4096 + tid * 8]);
    async16(Kh + (size_t)(64 + row) * 64 + gc * 8, &KVs[1][tid * 8]);
    async16(Vh + (size_t)row * 2048 + 64 + gc * 8, &KVs[1][4096 + tid * 8]);
  }

  const f32x4 fz = {0.f, 0.f, 0.f, 0.f};
  f32x4 o[2][4];        // [q-tile][d-tile]
  float lr[2];          // per-lane partial row sums, q = nt*16 + (lane&15)
#pragma unroll
  for (int nt = 0; nt < 2; ++nt) {
    lr[nt] = 0.f;
#pragma unroll
    for (int dt = 0; dt < 4; ++dt) o[nt][dt] = fz;
  }

  for (int j = 0; j < 32; ++j) {
    // own loads(j) retired (leaves loads(j+1) = 2 outstanding)
    asm volatile("s_waitcnt vmcnt(2)" ::: "memory");
    __builtin_amdgcn_s_barrier();   // ALL waves' loads(j) landed; all reads of
                                    // buf (j-1)%3 == (j+2)%3 retired
    asm volatile("" ::: "memory");
    // issue prefetch j+2 into buf (j+2)%3 (wrap past end: harmless junk)
    {
      int jj = (j + 2) & 31;
      unsigned short* nb = &KVs[(j + 2) % 3][0];
      int row = tid >> 3, cl = tid & 7, gc = cl ^ (row & 7);
      async16(Kh + (size_t)(jj * 64 + row) * 64 + gc * 8, &nb[tid * 8]);
      async16(Vh + (size_t)row * 2048 + jj * 64 + gc * 8, &nb[4096 + tid * 8]);
    }
    const unsigned short* Kt = &KVs[j % 3][0];
    const unsigned short* Vs = &KVs[j % 3][4096];

    // software-pipelined compute: MFMA clusters adjacent to independent trans work
    AK a0 = load_ak(Kt, 0, mrow, quad); ST t0 = qkmm(a0, qb);
    AK a1 = load_ak(Kt, 1, mrow, quad); ST t1 = qkmm(a1, qb);
    PAT p0 = expp(t0, lr);
    AK a2 = load_ak(Kt, 2, mrow, quad); ST t2 = qkmm(a2, qb);
    pv(Vs, 0, p0, o, mrow, quad);
    PAT p1 = expp(t1, lr);
    AK a3 = load_ak(Kt, 3, mrow, quad); ST t3 = qkmm(a3, qb);
    pv(Vs, 1, p1, o, mrow, quad);
    PAT p2 = expp(t2, lr);
    pv(Vs, 2, p2, o, mrow, quad);
    PAT p3 = expp(t3, lr);
    pv(Vs, 3, p3, o, mrow, quad);
  }

  // reduce lr across the 4 quads (each lane then holds full sum for q = nt*16 + mrow)
#pragma unroll
  for (int nt = 0; nt < 2; ++nt) {
    float v = lr[nt];
    v += __shfl_xor(v, 16);
    v += __shfl_xor(v, 32);
    lr[nt] = v;
  }

  // normalize + write AO [B][L][H*D] bf16
  // o[nt][dt][i] is row q_local = quad*4+i of tile nt; col d = dt*16 + mrow
  int b_ = bh >> 4, h = bh & 15;
#pragma unroll
  for (int nt = 0; nt < 2; ++nt)
#pragma unroll
    for (int i = 0; i < 4; ++i) {
      float inv = 1.f / __shfl(lr[nt], quad * 4 + i, 64);
      int qrow = q0 + w * 32 + nt * 16 + quad * 4 + i;
#pragma unroll
      for (int dt = 0; dt < 4; ++dt) {
        int d = dt * 16 + mrow;
        AO[((size_t)(b_ * 2048 + qrow)) * 1024 + h * 64 + d] = f2bf(o[nt][dt][i] * inv);
      }
    }
}

// ---------------- GEMM2: out = AO @ WoT^T + bo (3-stage + XCD swizzle) --------
__global__ __launch_bounds__(256) void k_gemm_out(
    const unsigned short* __restrict__ Ab, const unsigned short* __restrict__ WoT,
    const float* __restrict__ bo, float* __restrict__ out) {
  __shared__ __align__(16) unsigned short St[3][2][4096];
  const int tid = threadIdx.x;
  const int w = tid >> 6, lane = tid & 63;
  const int quad = lane >> 4, mrow = lane & 15;
  // XCD swizzle: 512 blocks, bijective; contiguous 64-chunk per XCD shares B panel
  const int lin = blockIdx.x + 64 * blockIdx.y;
  const int swz = (lin & 7) * 64 + (lin >> 3);
  const int m0 = (swz & 63) * 128, n0 = (swz >> 6) * 128;
  const int wr = (w >> 1) * 64, wc = (w & 1) * 64;
  const unsigned short* PA = Ab + (size_t)m0 * 1024;
  const unsigned short* PB = WoT + (size_t)n0 * 1024;

  auto issue = [&](int kt, int s) {
    int ktw = kt & 31;
#pragma unroll
    for (int r = 0; r < 2; ++r) {
      int c = r * 256 + tid;
      int row = c >> 2, cc = c & 3;
      async16(PA + (size_t)row * 1024 + ktw * 32 + cc * 8, &St[s][0][c * 8]);
      async16(PB + (size_t)row * 1024 + ktw * 32 + cc * 8, &St[s][1][c * 8]);
    }
  };

  const f32x4 fz = {0.f, 0.f, 0.f, 0.f};
  f32x4 acc[4][4];
#pragma unroll
  for (int a = 0; a < 4; ++a)
#pragma unroll
    for (int b = 0; b < 4; ++b) acc[a][b] = fz;

  issue(0, 0);
  issue(1, 1);

  for (int kt = 0; kt < 32; ++kt) {
    asm volatile("s_waitcnt vmcnt(4)" ::: "memory");
    __builtin_amdgcn_s_barrier();
    asm volatile("" ::: "memory");
    issue(kt + 2, (kt + 2) % 3);
    const unsigned short* As = &St[kt % 3][0][0];
    const unsigned short* Bs = &St[kt % 3][1][0];
    s16x8 a[4], b[4];
#pragma unroll
    for (int mt = 0; mt < 4; ++mt)
      a[mt] = *(const s16x8*)&As[(wr + mt * 16 + mrow) * 32 + quad * 8];
#pragma unroll
    for (int nt = 0; nt < 4; ++nt)
      b[nt] = *(const s16x8*)&Bs[(wc + nt * 16 + mrow) * 32 + quad * 8];
#pragma unroll
    for (int mt = 0; mt < 4; ++mt)
#pragma unroll
      for (int nt = 0; nt < 4; ++nt)
        acc[mt][nt] = __builtin_amdgcn_mfma_f32_16x16x32_bf16(a[mt], b[nt], acc[mt][nt], 0, 0, 0);
  }
#pragma unroll
  for (int mt = 0; mt < 4; ++mt)
#pragma unroll
    for (int nt = 0; nt < 4; ++nt)
#pragma unroll
      for (int i = 0; i < 4; ++i) {
        int row = m0 + wr + mt * 16 + quad * 4 + i;
        int col = n0 + wc + nt * 16 + mrow;
        out[(size_t)row * 1024 + col] = acc[mt][nt][i] + bo[col];
      }
}

extern "C" void kernel_launch(void* const* d_in, const int* in_sizes, int n_in,
                              void* d_out, int out_size, void* d_ws, size_t ws_size,
                              hipStream_t stream) {
  const float* x  = (const float*)d_in[0];
  const float* Wq = (const float*)d_in[1];
  const float* Wk = (const float*)d_in[2];
  const float* Wv = (const float*)d_in[3];
  const float* Wo = (const float*)d_in[4];
  const float* bo = (const float*)d_in[5];
  float* out = (float*)d_out;

  char* ws = (char*)d_ws;
  const size_t MiB = 1u << 20;
  unsigned short* xb  = (unsigned short*)(ws);              // 16 MiB, reused as AO
  unsigned short* Wt  = (unsigned short*)(ws + 16 * MiB);   // 6 MiB  (Wq^T|Wk^T|Wv^T)
  unsigned short* WoT = (unsigned short*)(ws + 22 * MiB);   // 2 MiB
  unsigned short* Qb  = (unsigned short*)(ws + 24 * MiB);   // 16 MiB [B,H,L,D]
  unsigned short* Kb  = (unsigned short*)(ws + 40 * MiB);   // 16 MiB [B,H,L,D] (pre-scaled)
  unsigned short* Vt  = (unsigned short*)(ws + 56 * MiB);   // 16 MiB [B,H,D,L]
  unsigned short* AO  = xb;  // x/xb no longer needed after the merged GEMM

  k_prep<<<12288, 256, 0, stream>>>(x, Wq, Wk, Wv, Wo, xb, Wt, WoT);
  k_gemm_qkvt<<<1536, 256, 0, stream>>>(xb, Wt, Qb, Kb, Vt);
  k_attn<<<dim3(8, 64), 512, 0, stream>>>(Qb, Kb, Vt, AO);
  k_gemm_out<<<dim3(64, 8), 256, 0, stream>>>(AO, WoT, bo, out);
}

// Round 7
// 268.959 us; speedup vs baseline: 1.0262x; 1.0193x over previous
//
#include <hip/hip_runtime.h>

// Problem constants
#define B_ 4
#define L_ 2048
#define E_ 1024
#define H_ 16
#define D_ 64
// scale = 1/sqrt(E) = 1/32; folded with log2(e) for exp2-based softmax.
// Baked into K in the GEMM-QK epilogue.
#define CSCALE 0.045084960222629414f

typedef short s16x8 __attribute__((ext_vector_type(8)));
typedef short s16x4 __attribute__((ext_vector_type(4)));
typedef float f32x4 __attribute__((ext_vector_type(4)));

__device__ __forceinline__ unsigned short f2bf(float f) {
  union { float f; unsigned int u; } v;
  v.f = f;
  unsigned int u = v.u;
  u += 0x7fffu + ((u >> 16) & 1u);   // round-to-nearest-even
  return (unsigned short)(u >> 16);
}

// async global->LDS, 16B per lane; HW dest = wave-uniform base + lane*16
__device__ __forceinline__ void async16(const void* g, void* l) {
  __builtin_amdgcn_global_load_lds(
      (__attribute__((address_space(1))) void*)(g),
      (__attribute__((address_space(3))) void*)(l), 16, 0, 0);
}

// ---------------- prep (fused): x fp32->bf16  +  4x W transpose ----------------
__global__ void k_prep(const float* __restrict__ x,
                       const float* __restrict__ Wq, const float* __restrict__ Wk,
                       const float* __restrict__ Wv, const float* __restrict__ Wo,
                       unsigned short* __restrict__ xb,
                       unsigned short* __restrict__ Wt, unsigned short* __restrict__ WoT) {
  __shared__ float t[32][33];
  int bid = blockIdx.x, tid = threadIdx.x;
  if (bid < 8192) {
    int i = bid * 256 + tid;
    float4 v = ((const float4*)x)[i];
    ushort4 o;
    o.x = f2bf(v.x); o.y = f2bf(v.y); o.z = f2bf(v.z); o.w = f2bf(v.w);
    ((ushort4*)xb)[i] = o;
    return;
  }
  int tt = bid - 8192;
  int wsel = tt >> 10, tile = tt & 1023;
  const float* in = (wsel == 0) ? Wq : (wsel == 1) ? Wk : (wsel == 2) ? Wv : Wo;
  unsigned short* out = (wsel == 0) ? Wt : (wsel == 1) ? Wt + (1u << 20)
                        : (wsel == 2) ? Wt + (2u << 20) : WoT;
  int bx = tile & 31, by = tile >> 5;
  int tx = tid & 31, ty = tid >> 5;   // 32 x 8
  int xcol = bx * 32 + tx;
  int y0 = by * 32;
#pragma unroll
  for (int i = 0; i < 4; ++i)
    t[ty + i * 8][tx] = in[(size_t)(y0 + ty + i * 8) * 1024 + xcol];
  __syncthreads();
  int xo = by * 32 + tx;
  int yo0 = bx * 32;
#pragma unroll
  for (int i = 0; i < 4; ++i)
    out[(size_t)(yo0 + ty + i * 8) * 1024 + xo] = f2bf(t[tx][ty + i * 8]);
}

// ---------------- merged GEMM: QK + VT -----------------------------------------
// Round-6 diagnosis: latency-bound (MfmaUtil 21, VALU 14, Occ 21) at 4-wave
// blocks / ~2 waves/SIMD -> nothing covers ds_read->MFMA + staging latency.
// v2: 256x128 tile, 512 threads (8 waves, wave=64x64), 3-stage counted vmcnt
// (vmcnt(3) = one 3-load stage ahead), LDS 72KB -> 2 blocks/CU = 16 waves/CU.
// Read-side chunk XOR swizzle (quad^(row&3)) with pre-swizzled global source
// (both-sides rule): 8-way -> 4-way LDS bank conflict on ds_read_b128.
// Grid 768 = 512 QK + 256 VT, bijective XCD swizzle (768%8==0).
__global__ __launch_bounds__(512) void k_gemm_qkvt(
    const unsigned short* __restrict__ xb, const unsigned short* __restrict__ Wt,
    unsigned short* __restrict__ Qb, unsigned short* __restrict__ Kb,
    unsigned short* __restrict__ Vt) {
  __shared__ __align__(16) unsigned short St[3][12288];  // [stage][A 256x32 | B 128x32]
  const int bid0 = blockIdx.x;
  const int bid = (bid0 & 7) * 96 + (bid0 >> 3);   // XCD swizzle, bijective (768)
  const int tid = threadIdx.x;
  const int w = tid >> 6, lane = tid & 63;
  const int quad = lane >> 4, mrow = lane & 15;
  const bool isQK = bid < 512;
  int m0, n0;
  const unsigned short *PA, *PB;
  if (isQK) {
    m0 = (bid & 31) * 256;           // token
    n0 = (bid >> 5) * 128;           // feature in [0,2048)
    PA = xb + (size_t)m0 * 1024;
    PB = Wt + (size_t)n0 * 1024;
  } else {
    int g = bid - 512;
    m0 = (g & 3) * 256;              // feature (h*64+d)
    n0 = (g >> 2) * 128;             // token
    PA = Wt + (2u << 20) + (size_t)m0 * 1024;   // WvT
    PB = xb + (size_t)n0 * 1024;
  }
  const int wr = (w >> 1) * 64, wc = (w & 1) * 64;

  // stage issue: 3 async16/thread (A 2 + B 1); source chunk pre-swizzled
  auto issue = [&](int kt, int s) {
    int ktw = kt & 31;   // wrap past the end: junk prefetch, keeps vmcnt uniform
#pragma unroll
    for (int r = 0; r < 2; ++r) {
      int c = r * 512 + tid;           // A: 1024 chunks (256 rows x 4)
      int row = c >> 2, cl = c & 3, gc = cl ^ (row & 3);
      async16(PA + (size_t)row * 1024 + ktw * 32 + gc * 8, &St[s][c * 8]);
    }
    {
      int c = tid;                      // B: 512 chunks (128 rows x 4)
      int row = c >> 2, cl = c & 3, gc = cl ^ (row & 3);
      async16(PB + (size_t)row * 1024 + ktw * 32 + gc * 8, &St[s][8192 + c * 8]);
    }
  };

  const f32x4 fz = {0.f, 0.f, 0.f, 0.f};
  f32x4 acc[4][4];
#pragma unroll
  for (int a = 0; a < 4; ++a)
#pragma unroll
    for (int b = 0; b < 4; ++b) acc[a][b] = fz;

  // prologue: fill stages 0,1
  issue(0, 0);
  issue(1, 1);

  for (int kt = 0; kt < 32; ++kt) {
    // own stage(kt) retired (leaves stage(kt+1) = 3 outstanding)
    asm volatile("s_waitcnt vmcnt(3)" ::: "memory");
    __builtin_amdgcn_s_barrier();   // all waves' stage(kt) landed; all reads of
                                    // stage (kt+2)%3 (iter kt-1) retired
    asm volatile("" ::: "memory");
    issue(kt + 2, (kt + 2) % 3);
    const unsigned short* As = &St[kt % 3][0];
    const unsigned short* Bs = &St[kt % 3][8192];
    s16x8 a[4], b[4];
#pragma unroll
    for (int mt = 0; mt < 4; ++mt) {
      int row = wr + mt * 16 + mrow;
      a[mt] = *(const s16x8*)&As[row * 32 + ((quad ^ (row & 3)) << 3)];
    }
#pragma unroll
    for (int nt = 0; nt < 4; ++nt) {
      int row = wc + nt * 16 + mrow;
      b[nt] = *(const s16x8*)&Bs[row * 32 + ((quad ^ (row & 3)) << 3)];
    }
#pragma unroll
    for (int mt = 0; mt < 4; ++mt)
#pragma unroll
      for (int nt = 0; nt < 4; ++nt)
        acc[mt][nt] = __builtin_amdgcn_mfma_f32_16x16x32_bf16(a[mt], b[nt], acc[mt][nt], 0, 0, 0);
  }
  // epilogue: C/D layout col=lane&15, row=quad*4+i
  if (isQK) {
#pragma unroll
    for (int mt = 0; mt < 4; ++mt)
#pragma unroll
      for (int nt = 0; nt < 4; ++nt)
#pragma unroll
        for (int i = 0; i < 4; ++i) {
          int row = m0 + wr + mt * 16 + quad * 4 + i;   // token
          int col = n0 + wc + nt * 16 + mrow;           // feature
          int bb = row >> 11, l = row & 2047;
          if (col < 1024) {
            int h = col >> 6, d = col & 63;
            Qb[(((size_t)(bb * 16 + h)) * 2048 + l) * 64 + d] = f2bf(acc[mt][nt][i]);
          } else {
            int c2 = col - 1024, h = c2 >> 6, d = c2 & 63;
            Kb[(((size_t)(bb * 16 + h)) * 2048 + l) * 64 + d] = f2bf(acc[mt][nt][i] * CSCALE);
          }
        }
  } else {
#pragma unroll
    for (int mt = 0; mt < 4; ++mt)
#pragma unroll
      for (int nt = 0; nt < 4; ++nt)
#pragma unroll
        for (int i = 0; i < 4; ++i) {
          int f = m0 + wr + mt * 16 + quad * 4 + i;     // feature
          int tk = n0 + wc + nt * 16 + mrow;            // token
          int bb = tk >> 11, l = tk & 2047;
          Vt[((size_t)(bb * 1024 + f)) * 2048 + l] = f2bf(acc[mt][nt][i]);
        }
  }
}

// ---------------- flash attention (r6 proven, unchanged: ~90.4us) --------------
struct AK { s16x8 k0, k1; };
struct ST { f32x4 s0, s1; };
struct PAT { s16x4 n0, n1; };

__device__ __forceinline__ AK load_ak(const unsigned short* Kt, int mt, int mrow, int quad) {
  int row = mt * 16 + mrow;
  AK r;
  r.k0 = *(const s16x8*)&Kt[row * 64 + (((0 + quad) ^ (row & 7)) << 3)];
  r.k1 = *(const s16x8*)&Kt[row * 64 + (((4 + quad) ^ (row & 7)) << 3)];
  return r;
}

__device__ __forceinline__ ST qkmm(const AK& a, const s16x8 (&qb)[2][2]) {
  const f32x4 fz = {0.f, 0.f, 0.f, 0.f};
  ST t; t.s0 = fz; t.s1 = fz;
  __builtin_amdgcn_s_setprio(1);
  t.s0 = __builtin_amdgcn_mfma_f32_16x16x32_bf16(a.k0, qb[0][0], t.s0, 0, 0, 0);
  t.s1 = __builtin_amdgcn_mfma_f32_16x16x32_bf16(a.k0, qb[1][0], t.s1, 0, 0, 0);
  t.s0 = __builtin_amdgcn_mfma_f32_16x16x32_bf16(a.k1, qb[0][1], t.s0, 0, 0, 0);
  t.s1 = __builtin_amdgcn_mfma_f32_16x16x32_bf16(a.k1, qb[1][1], t.s1, 0, 0, 0);
  __builtin_amdgcn_s_setprio(0);
  return t;
}

__device__ __forceinline__ s16x4 exp_pack(const f32x4 sv, float& lracc) {
  float p0 = __builtin_amdgcn_exp2f(sv[0]);
  float p1 = __builtin_amdgcn_exp2f(sv[1]);
  float p2 = __builtin_amdgcn_exp2f(sv[2]);
  float p3 = __builtin_amdgcn_exp2f(sv[3]);
  lracc += (p0 + p1) + (p2 + p3);
  unsigned int r01, r23;
  asm("v_cvt_pk_bf16_f32 %0, %1, %2" : "=v"(r01) : "v"(p0), "v"(p1));
  asm("v_cvt_pk_bf16_f32 %0, %1, %2" : "=v"(r23) : "v"(p2), "v"(p3));
  union { unsigned int u[2]; s16x4 v4; } uu;
  uu.u[0] = r01; uu.u[1] = r23;
  return uu.v4;
}

__device__ __forceinline__ PAT expp(const ST& t, float (&lr)[2]) {
  PAT r;
  r.n0 = exp_pack(t.s0, lr[0]);
  r.n1 = exp_pack(t.s1, lr[1]);
  return r;
}

__device__ __forceinline__ void pv(const unsigned short* Vs, int lt, const PAT& p,
                                   f32x4 (&o)[2][4], int mrow, int quad) {
  s16x4 vb[4];
  int lbase = lt * 16 + quad * 4;
  int cg = lbase >> 3, off = lbase & 7;
#pragma unroll
  for (int dt = 0; dt < 4; ++dt) {
    int row = dt * 16 + mrow;
    vb[dt] = *(const s16x4*)&Vs[row * 64 + ((cg ^ (row & 7)) << 3) + off];
  }
  __builtin_amdgcn_s_setprio(1);
#pragma unroll
  for (int dt = 0; dt < 4; ++dt) {
    o[0][dt] = __builtin_amdgcn_mfma_f32_16x16x16bf16_1k(p.n0, vb[dt], o[0][dt], 0, 0, 0);
    o[1][dt] = __builtin_amdgcn_mfma_f32_16x16x16bf16_1k(p.n1, vb[dt], o[1][dt], 0, 0, 0);
  }
  __builtin_amdgcn_s_setprio(0);
}

__global__ __launch_bounds__(512) void k_attn(
    const unsigned short* __restrict__ Qb, const unsigned short* __restrict__ Kb,
    const unsigned short* __restrict__ Vt, unsigned short* __restrict__ AO) {
  __shared__ __align__(16) unsigned short KVs[3][8192];  // per buf: [K 8KB | V 8KB]
  const int tid = threadIdx.x, w = tid >> 6, lane = tid & 63;
  const int quad = lane >> 4, mrow = lane & 15;
  // XCD swizzle: lin = x + 8*y (x fastest in dispatch); swz chunks 64 blocks/XCD
  const int lin = blockIdx.x + 8 * blockIdx.y;
  const int swz = (lin & 7) * 64 + (lin >> 3);   // 512 % 8 == 0 -> bijective
  const int bh = swz >> 3;
  const int q0 = (swz & 7) * 256;
  const unsigned short* Qh = Qb + (size_t)bh * 2048 * 64;
  const unsigned short* Kh = Kb + (size_t)bh * 2048 * 64;
  const unsigned short* Vh = Vt + (size_t)bh * 64 * 2048;
  unsigned short* KVf = &KVs[0][0];

  // stage Q tile [256][64] through bufs 0-1 (32KB), swizzled
#pragma unroll
  for (int r = 0; r < 4; ++r) {
    int c = r * 512 + tid;       // 2048 chunks
    int row = c >> 3, cl = c & 7;
    int gc = cl ^ (row & 7);
    async16(Qh + (size_t)(q0 + row) * 64 + gc * 8, &KVf[c * 8]);
  }
  asm volatile("s_waitcnt vmcnt(0)" ::: "memory");
  __builtin_amdgcn_s_barrier();
  asm volatile("" ::: "memory");
  // Q B-frags (persist in regs): B[n=q][k=d], q = w*32 + nt*16 + mrow
  s16x8 qb[2][2];
#pragma unroll
  for (int nt = 0; nt < 2; ++nt)
#pragma unroll
    for (int ks = 0; ks < 2; ++ks) {
      int row = w * 32 + nt * 16 + mrow;
      qb[nt][ks] = *(const s16x8*)&KVf[row * 64 + (((ks * 4 + quad) ^ (row & 7)) << 3)];
    }
  asm volatile("" ::: "memory");
  __builtin_amdgcn_s_barrier();   // all waves done reading Q; bufs free
  asm volatile("" ::: "memory");

  // prologue: issue j=0 -> buf0, j=1 -> buf1 (2 async16/thread each)
  {
    int row = tid >> 3, cl = tid & 7, gc = cl ^ (row & 7);
    async16(Kh + (size_t)row * 64 + gc * 8, &KVs[0][tid * 8]);
    async16(Vh + (size_t)row * 2048 + gc * 8, &KVs[0][4096 + tid * 8]);
    async16(Kh + (size_t)(64 + row) * 64 + gc * 8, &KVs[1][tid * 8]);
    async16(Vh + (size_t)row * 2048 + 64 + gc * 8, &KVs[1][4096 + tid * 8]);
  }

  const f32x4 fz = {0.f, 0.f, 0.f, 0.f};
  f32x4 o[2][4];        // [q-tile][d-tile]
  float lr[2];          // per-lane partial row sums, q = nt*16 + (lane&15)
#pragma unroll
  for (int nt = 0; nt < 2; ++nt) {
    lr[nt] = 0.f;
#pragma unroll
    for (int dt = 0; dt < 4; ++dt) o[nt][dt] = fz;
  }

  for (int j = 0; j < 32; ++j) {
    // own loads(j) retired (leaves loads(j+1) = 2 outstanding)
    asm volatile("s_waitcnt vmcnt(2)" ::: "memory");
    __builtin_amdgcn_s_barrier();   // ALL waves' loads(j) landed; all reads of
                                    // buf (j-1)%3 == (j+2)%3 retired
    asm volatile("" ::: "memory");
    // issue prefetch j+2 into buf (j+2)%3 (wrap past end: harmless junk)
    {
      int jj = (j + 2) & 31;
      unsigned short* nb = &KVs[(j + 2) % 3][0];
      int row = tid >> 3, cl = tid & 7, gc = cl ^ (row & 7);
      async16(Kh + (size_t)(jj * 64 + row) * 64 + gc * 8, &nb[tid * 8]);
      async16(Vh + (size_t)row * 2048 + jj * 64 + gc * 8, &nb[4096 + tid * 8]);
    }
    const unsigned short* Kt = &KVs[j % 3][0];
    const unsigned short* Vs = &KVs[j % 3][4096];

    // software-pipelined compute: MFMA clusters adjacent to independent trans work
    AK a0 = load_ak(Kt, 0, mrow, quad); ST t0 = qkmm(a0, qb);
    AK a1 = load_ak(Kt, 1, mrow, quad); ST t1 = qkmm(a1, qb);
    PAT p0 = expp(t0, lr);
    AK a2 = load_ak(Kt, 2, mrow, quad); ST t2 = qkmm(a2, qb);
    pv(Vs, 0, p0, o, mrow, quad);
    PAT p1 = expp(t1, lr);
    AK a3 = load_ak(Kt, 3, mrow, quad); ST t3 = qkmm(a3, qb);
    pv(Vs, 1, p1, o, mrow, quad);
    PAT p2 = expp(t2, lr);
    pv(Vs, 2, p2, o, mrow, quad);
    PAT p3 = expp(t3, lr);
    pv(Vs, 3, p3, o, mrow, quad);
  }

  // reduce lr across the 4 quads (each lane then holds full sum for q = nt*16 + mrow)
#pragma unroll
  for (int nt = 0; nt < 2; ++nt) {
    float v = lr[nt];
    v += __shfl_xor(v, 16);
    v += __shfl_xor(v, 32);
    lr[nt] = v;
  }

  // normalize + write AO [B][L][H*D] bf16
  // o[nt][dt][i] is row q_local = quad*4+i of tile nt; col d = dt*16 + mrow
  int b_ = bh >> 4, h = bh & 15;
#pragma unroll
  for (int nt = 0; nt < 2; ++nt)
#pragma unroll
    for (int i = 0; i < 4; ++i) {
      float inv = 1.f / __shfl(lr[nt], quad * 4 + i, 64);
      int qrow = q0 + w * 32 + nt * 16 + quad * 4 + i;
#pragma unroll
      for (int dt = 0; dt < 4; ++dt) {
        int d = dt * 16 + mrow;
        AO[((size_t)(b_ * 2048 + qrow)) * 1024 + h * 64 + d] = f2bf(o[nt][dt][i] * inv);
      }
    }
}

// ---------------- GEMM2: out = AO @ WoT^T + bo --------------------------------
// v2: 512 threads (8 waves, wave=32x64), 3-stage (48KB -> 3 blocks/CU),
// vmcnt(2), chunk swizzle, XCD swizzle. Same latency-hiding rationale as qkvt.
__global__ __launch_bounds__(512) void k_gemm_out(
    const unsigned short* __restrict__ Ab, const unsigned short* __restrict__ WoT,
    const float* __restrict__ bo, float* __restrict__ out) {
  __shared__ __align__(16) unsigned short St[3][8192];  // [stage][A 128x32 | B 128x32]
  const int tid = threadIdx.x;
  const int w = tid >> 6, lane = tid & 63;
  const int quad = lane >> 4, mrow = lane & 15;
  const int lin = blockIdx.x + 64 * blockIdx.y;
  const int swz = (lin & 7) * 64 + (lin >> 3);   // 512 % 8 == 0 -> bijective
  const int m0 = (swz & 63) * 128, n0 = (swz >> 6) * 128;
  const int wr = (w >> 1) * 32, wc = (w & 1) * 64;   // wave = 32x64 out
  const unsigned short* PA = Ab + (size_t)m0 * 1024;
  const unsigned short* PB = WoT + (size_t)n0 * 1024;

  auto issue = [&](int kt, int s) {
    int ktw = kt & 31;
    {
      int c = tid;                      // A: 512 chunks
      int row = c >> 2, cl = c & 3, gc = cl ^ (row & 3);
      async16(PA + (size_t)row * 1024 + ktw * 32 + gc * 8, &St[s][c * 8]);
    }
    {
      int c = tid;                      // B: 512 chunks
      int row = c >> 2, cl = c & 3, gc = cl ^ (row & 3);
      async16(PB + (size_t)row * 1024 + ktw * 32 + gc * 8, &St[s][4096 + c * 8]);
    }
  };

  const f32x4 fz = {0.f, 0.f, 0.f, 0.f};
  f32x4 acc[2][4];
#pragma unroll
  for (int a = 0; a < 2; ++a)
#pragma unroll
    for (int b = 0; b < 4; ++b) acc[a][b] = fz;

  issue(0, 0);
  issue(1, 1);

  for (int kt = 0; kt < 32; ++kt) {
    asm volatile("s_waitcnt vmcnt(2)" ::: "memory");
    __builtin_amdgcn_s_barrier();
    asm volatile("" ::: "memory");
    issue(kt + 2, (kt + 2) % 3);
    const unsigned short* As = &St[kt % 3][0];
    const unsigned short* Bs = &St[kt % 3][4096];
    s16x8 a[2], b[4];
#pragma unroll
    for (int mt = 0; mt < 2; ++mt) {
      int row = wr + mt * 16 + mrow;
      a[mt] = *(const s16x8*)&As[row * 32 + ((quad ^ (row & 3)) << 3)];
    }
#pragma unroll
    for (int nt = 0; nt < 4; ++nt) {
      int row = wc + nt * 16 + mrow;
      b[nt] = *(const s16x8*)&Bs[row * 32 + ((quad ^ (row & 3)) << 3)];
    }
#pragma unroll
    for (int mt = 0; mt < 2; ++mt)
#pragma unroll
      for (int nt = 0; nt < 4; ++nt)
        acc[mt][nt] = __builtin_amdgcn_mfma_f32_16x16x32_bf16(a[mt], b[nt], acc[mt][nt], 0, 0, 0);
  }
#pragma unroll
  for (int mt = 0; mt < 2; ++mt)
#pragma unroll
    for (int nt = 0; nt < 4; ++nt)
#pragma unroll
      for (int i = 0; i < 4; ++i) {
        int row = m0 + wr + mt * 16 + quad * 4 + i;
        int col = n0 + wc + nt * 16 + mrow;
        out[(size_t)row * 1024 + col] = acc[mt][nt][i] + bo[col];
      }
}

extern "C" void kernel_launch(void* const* d_in, const int* in_sizes, int n_in,
                              void* d_out, int out_size, void* d_ws, size_t ws_size,
                              hipStream_t stream) {
  const float* x  = (const float*)d_in[0];
  const float* Wq = (const float*)d_in[1];
  const float* Wk = (const float*)d_in[2];
  const float* Wv = (const float*)d_in[3];
  const float* Wo = (const float*)d_in[4];
  const float* bo = (const float*)d_in[5];
  float* out = (float*)d_out;

  char* ws = (char*)d_ws;
  const size_t MiB = 1u << 20;
  unsigned short* xb  = (unsigned short*)(ws);              // 16 MiB, reused as AO
  unsigned short* Wt  = (unsigned short*)(ws + 16 * MiB);   // 6 MiB  (Wq^T|Wk^T|Wv^T)
  unsigned short* WoT = (unsigned short*)(ws + 22 * MiB);   // 2 MiB
  unsigned short* Qb  = (unsigned short*)(ws + 24 * MiB);   // 16 MiB [B,H,L,D]
  unsigned short* Kb  = (unsigned short*)(ws + 40 * MiB);   // 16 MiB [B,H,L,D] (pre-scaled)
  unsigned short* Vt  = (unsigned short*)(ws + 56 * MiB);   // 16 MiB [B,H,D,L]
  unsigned short* AO  = xb;  // x/xb no longer needed after the merged GEMM

  k_prep<<<12288, 256, 0, stream>>>(x, Wq, Wk, Wv, Wo, xb, Wt, WoT);
  k_gemm_qkvt<<<768, 512, 0, stream>>>(xb, Wt, Qb, Kb, Vt);
  k_attn<<<dim3(8, 64), 512, 0, stream>>>(Qb, Kb, Vt, AO);
  k_gemm_out<<<dim3(64, 8), 512, 0, stream>>>(AO, WoT, bo, out);
}

// Round 8
// 260.527 us; speedup vs baseline: 1.0594x; 1.0324x over previous
//
#include <hip/hip_runtime.h>

// Problem constants
#define B_ 4
#define L_ 2048
#define E_ 1024
#define H_ 16
#define D_ 64
// scale = 1/sqrt(E) = 1/32; folded with log2(e) for exp2-based softmax.
// Baked into K in the GEMM-QK epilogue.
#define CSCALE 0.045084960222629414f

typedef short s16x8 __attribute__((ext_vector_type(8)));
typedef short s16x4 __attribute__((ext_vector_type(4)));
typedef float f32x4 __attribute__((ext_vector_type(4)));

__device__ __forceinline__ unsigned short f2bf(float f) {
  union { float f; unsigned int u; } v;
  v.f = f;
  unsigned int u = v.u;
  u += 0x7fffu + ((u >> 16) & 1u);   // round-to-nearest-even
  return (unsigned short)(u >> 16);
}

// async global->LDS, 16B per lane; HW dest = wave-uniform base + lane*16
__device__ __forceinline__ void async16(const void* g, void* l) {
  __builtin_amdgcn_global_load_lds(
      (__attribute__((address_space(1))) void*)(g),
      (__attribute__((address_space(3))) void*)(l), 16, 0, 0);
}

// ---------------- prep (fused): x fp32->bf16  +  4x W transpose ----------------
__global__ void k_prep(const float* __restrict__ x,
                       const float* __restrict__ Wq, const float* __restrict__ Wk,
                       const float* __restrict__ Wv, const float* __restrict__ Wo,
                       unsigned short* __restrict__ xb,
                       unsigned short* __restrict__ Wt, unsigned short* __restrict__ WoT) {
  __shared__ float t[32][33];
  int bid = blockIdx.x, tid = threadIdx.x;
  if (bid < 8192) {
    int i = bid * 256 + tid;
    float4 v = ((const float4*)x)[i];
    ushort4 o;
    o.x = f2bf(v.x); o.y = f2bf(v.y); o.z = f2bf(v.z); o.w = f2bf(v.w);
    ((ushort4*)xb)[i] = o;
    return;
  }
  int tt = bid - 8192;
  int wsel = tt >> 10, tile = tt & 1023;
  const float* in = (wsel == 0) ? Wq : (wsel == 1) ? Wk : (wsel == 2) ? Wv : Wo;
  unsigned short* out = (wsel == 0) ? Wt : (wsel == 1) ? Wt + (1u << 20)
                        : (wsel == 2) ? Wt + (2u << 20) : WoT;
  int bx = tile & 31, by = tile >> 5;
  int tx = tid & 31, ty = tid >> 5;   // 32 x 8
  int xcol = bx * 32 + tx;
  int y0 = by * 32;
#pragma unroll
  for (int i = 0; i < 4; ++i)
    t[ty + i * 8][tx] = in[(size_t)(y0 + ty + i * 8) * 1024 + xcol];
  __syncthreads();
  int xo = by * 32 + tx;
  int yo0 = bx * 32;
#pragma unroll
  for (int i = 0; i < 4; ++i)
    out[(size_t)(yo0 + ty + i * 8) * 1024 + xo] = f2bf(t[tx][ty + i * 8]);
}

// ---------------- merged GEMM: QK + VT -----------------------------------------
// Round-7 lesson: 72KB 3-stage = 2 blocks/CU resident vs grid 768 = 3/CU of
// work -> second dispatch round at half occupancy (tail). v3: 2-stage 48KB ->
// 3 blocks/CU, grid 768 = 256x3 EXACTLY resident, 24 waves/CU (6/SIMD).
// Counted pipeline kept at prefetch-distance 2 over 2 stages:
//   prologue: issue(0->s0), issue(1->s1)
//   iter kt:  vmcnt(3)  [loads(kt) landed; loads(kt+1) still in flight]
//             barrier   [all waves' loads(kt) landed]
//             compute(kt) from stage kt&1
//             barrier   [all waves done reading stage kt&1]
//             issue(kt+2 -> stage kt&1)   [race-free overwrite]
// vmcnt never drains to 0. bid remap: n0 fastest within each XCD's 96-block
// chunk -> 6 A-panels (3MB, L2-fit) per chunk instead of streaming all of A.
__global__ __launch_bounds__(512) void k_gemm_qkvt(
    const unsigned short* __restrict__ xb, const unsigned short* __restrict__ Wt,
    unsigned short* __restrict__ Qb, unsigned short* __restrict__ Kb,
    unsigned short* __restrict__ Vt) {
  __shared__ __align__(16) unsigned short St[2][12288];  // [stage][A 256x32 | B 128x32]
  const int bid0 = blockIdx.x;
  const int bid = (bid0 & 7) * 96 + (bid0 >> 3);   // XCD swizzle, bijective (768)
  const int tid = threadIdx.x;
  const int w = tid >> 6, lane = tid & 63;
  const int quad = lane >> 4, mrow = lane & 15;
  const bool isQK = bid < 512;
  int m0, n0;
  const unsigned short *PA, *PB;
  if (isQK) {
    m0 = (bid >> 4) * 256;           // token (32 panels; 6 per XCD chunk -> L2)
    n0 = (bid & 15) * 128;           // feature in [0,2048)
    PA = xb + (size_t)m0 * 1024;
    PB = Wt + (size_t)n0 * 1024;
  } else {
    int g = bid - 512;
    m0 = (g >> 6) * 256;             // feature (h*64+d), 4 panels
    n0 = (g & 63) * 128;             // token
    PA = Wt + (2u << 20) + (size_t)m0 * 1024;   // WvT
    PB = xb + (size_t)n0 * 1024;
  }
  const int wr = (w >> 1) * 64, wc = (w & 1) * 64;

  // stage issue: 3 async16/thread (A 2 + B 1); source chunk pre-swizzled
  auto issue = [&](int kt, int s) {
    int ktw = kt & 31;   // wrap past the end: junk prefetch, keeps vmcnt uniform
#pragma unroll
    for (int r = 0; r < 2; ++r) {
      int c = r * 512 + tid;           // A: 1024 chunks (256 rows x 4)
      int row = c >> 2, cl = c & 3, gc = cl ^ (row & 3);
      async16(PA + (size_t)row * 1024 + ktw * 32 + gc * 8, &St[s][c * 8]);
    }
    {
      int c = tid;                      // B: 512 chunks (128 rows x 4)
      int row = c >> 2, cl = c & 3, gc = cl ^ (row & 3);
      async16(PB + (size_t)row * 1024 + ktw * 32 + gc * 8, &St[s][8192 + c * 8]);
    }
  };

  const f32x4 fz = {0.f, 0.f, 0.f, 0.f};
  f32x4 acc[4][4];
#pragma unroll
  for (int a = 0; a < 4; ++a)
#pragma unroll
    for (int b = 0; b < 4; ++b) acc[a][b] = fz;

  // prologue: fill both stages
  issue(0, 0);
  issue(1, 1);

  for (int kt = 0; kt < 32; ++kt) {
    // loads(kt) retired (loads(kt+1) = 3 still outstanding; never drain to 0)
    asm volatile("s_waitcnt vmcnt(3)" ::: "memory");
    __builtin_amdgcn_s_barrier();
    asm volatile("" ::: "memory");
    const unsigned short* As = &St[kt & 1][0];
    const unsigned short* Bs = &St[kt & 1][8192];
    s16x8 a[4], b[4];
#pragma unroll
    for (int mt = 0; mt < 4; ++mt) {
      int row = wr + mt * 16 + mrow;
      a[mt] = *(const s16x8*)&As[row * 32 + ((quad ^ (row & 3)) << 3)];
    }
#pragma unroll
    for (int nt = 0; nt < 4; ++nt) {
      int row = wc + nt * 16 + mrow;
      b[nt] = *(const s16x8*)&Bs[row * 32 + ((quad ^ (row & 3)) << 3)];
    }
#pragma unroll
    for (int mt = 0; mt < 4; ++mt)
#pragma unroll
      for (int nt = 0; nt < 4; ++nt)
        acc[mt][nt] = __builtin_amdgcn_mfma_f32_16x16x32_bf16(a[mt], b[nt], acc[mt][nt], 0, 0, 0);
    // all waves done reading stage kt&1 -> safe to overwrite with loads(kt+2)
    asm volatile("" ::: "memory");
    __builtin_amdgcn_s_barrier();
    asm volatile("" ::: "memory");
    issue(kt + 2, kt & 1);
  }
  // epilogue: C/D layout col=lane&15, row=quad*4+i
  if (isQK) {
#pragma unroll
    for (int mt = 0; mt < 4; ++mt)
#pragma unroll
      for (int nt = 0; nt < 4; ++nt)
#pragma unroll
        for (int i = 0; i < 4; ++i) {
          int row = m0 + wr + mt * 16 + quad * 4 + i;   // token
          int col = n0 + wc + nt * 16 + mrow;           // feature
          int bb = row >> 11, l = row & 2047;
          if (col < 1024) {
            int h = col >> 6, d = col & 63;
            Qb[(((size_t)(bb * 16 + h)) * 2048 + l) * 64 + d] = f2bf(acc[mt][nt][i]);
          } else {
            int c2 = col - 1024, h = c2 >> 6, d = c2 & 63;
            Kb[(((size_t)(bb * 16 + h)) * 2048 + l) * 64 + d] = f2bf(acc[mt][nt][i] * CSCALE);
          }
        }
  } else {
#pragma unroll
    for (int mt = 0; mt < 4; ++mt)
#pragma unroll
      for (int nt = 0; nt < 4; ++nt)
#pragma unroll
        for (int i = 0; i < 4; ++i) {
          int f = m0 + wr + mt * 16 + quad * 4 + i;     // feature
          int tk = n0 + wc + nt * 16 + mrow;            // token
          int bb = tk >> 11, l = tk & 2047;
          Vt[((size_t)(bb * 1024 + f)) * 2048 + l] = f2bf(acc[mt][nt][i]);
        }
  }
}

// ---------------- flash attention (r6 proven, unchanged: ~89.5us) --------------
struct AK { s16x8 k0, k1; };
struct ST { f32x4 s0, s1; };
struct PAT { s16x4 n0, n1; };

__device__ __forceinline__ AK load_ak(const unsigned short* Kt, int mt, int mrow, int quad) {
  int row = mt * 16 + mrow;
  AK r;
  r.k0 = *(const s16x8*)&Kt[row * 64 + (((0 + quad) ^ (row & 7)) << 3)];
  r.k1 = *(const s16x8*)&Kt[row * 64 + (((4 + quad) ^ (row & 7)) << 3)];
  return r;
}

__device__ __forceinline__ ST qkmm(const AK& a, const s16x8 (&qb)[2][2]) {
  const f32x4 fz = {0.f, 0.f, 0.f, 0.f};
  ST t; t.s0 = fz; t.s1 = fz;
  __builtin_amdgcn_s_setprio(1);
  t.s0 = __builtin_amdgcn_mfma_f32_16x16x32_bf16(a.k0, qb[0][0], t.s0, 0, 0, 0);
  t.s1 = __builtin_amdgcn_mfma_f32_16x16x32_bf16(a.k0, qb[1][0], t.s1, 0, 0, 0);
  t.s0 = __builtin_amdgcn_mfma_f32_16x16x32_bf16(a.k1, qb[0][1], t.s0, 0, 0, 0);
  t.s1 = __builtin_amdgcn_mfma_f32_16x16x32_bf16(a.k1, qb[1][1], t.s1, 0, 0, 0);
  __builtin_amdgcn_s_setprio(0);
  return t;
}

__device__ __forceinline__ s16x4 exp_pack(const f32x4 sv, float& lracc) {
  float p0 = __builtin_amdgcn_exp2f(sv[0]);
  float p1 = __builtin_amdgcn_exp2f(sv[1]);
  float p2 = __builtin_amdgcn_exp2f(sv[2]);
  float p3 = __builtin_amdgcn_exp2f(sv[3]);
  lracc += (p0 + p1) + (p2 + p3);
  unsigned int r01, r23;
  asm("v_cvt_pk_bf16_f32 %0, %1, %2" : "=v"(r01) : "v"(p0), "v"(p1));
  asm("v_cvt_pk_bf16_f32 %0, %1, %2" : "=v"(r23) : "v"(p2), "v"(p3));
  union { unsigned int u[2]; s16x4 v4; } uu;
  uu.u[0] = r01; uu.u[1] = r23;
  return uu.v4;
}

__device__ __forceinline__ PAT expp(const ST& t, float (&lr)[2]) {
  PAT r;
  r.n0 = exp_pack(t.s0, lr[0]);
  r.n1 = exp_pack(t.s1, lr[1]);
  return r;
}

__device__ __forceinline__ void pv(const unsigned short* Vs, int lt, const PAT& p,
                                   f32x4 (&o)[2][4], int mrow, int quad) {
  s16x4 vb[4];
  int lbase = lt * 16 + quad * 4;
  int cg = lbase >> 3, off = lbase & 7;
#pragma unroll
  for (int dt = 0; dt < 4; ++dt) {
    int row = dt * 16 + mrow;
    vb[dt] = *(const s16x4*)&Vs[row * 64 + ((cg ^ (row & 7)) << 3) + off];
  }
  __builtin_amdgcn_s_setprio(1);
#pragma unroll
  for (int dt = 0; dt < 4; ++dt) {
    o[0][dt] = __builtin_amdgcn_mfma_f32_16x16x16bf16_1k(p.n0, vb[dt], o[0][dt], 0, 0, 0);
    o[1][dt] = __builtin_amdgcn_mfma_f32_16x16x16bf16_1k(p.n1, vb[dt], o[1][dt], 0, 0, 0);
  }
  __builtin_amdgcn_s_setprio(0);
}

__global__ __launch_bounds__(512) void k_attn(
    const unsigned short* __restrict__ Qb, const unsigned short* __restrict__ Kb,
    const unsigned short* __restrict__ Vt, unsigned short* __restrict__ AO) {
  __shared__ __align__(16) unsigned short KVs[3][8192];  // per buf: [K 8KB | V 8KB]
  const int tid = threadIdx.x, w = tid >> 6, lane = tid & 63;
  const int quad = lane >> 4, mrow = lane & 15;
  // XCD swizzle: lin = x + 8*y (x fastest in dispatch); swz chunks 64 blocks/XCD
  const int lin = blockIdx.x + 8 * blockIdx.y;
  const int swz = (lin & 7) * 64 + (lin >> 3);   // 512 % 8 == 0 -> bijective
  const int bh = swz >> 3;
  const int q0 = (swz & 7) * 256;
  const unsigned short* Qh = Qb + (size_t)bh * 2048 * 64;
  const unsigned short* Kh = Kb + (size_t)bh * 2048 * 64;
  const unsigned short* Vh = Vt + (size_t)bh * 64 * 2048;
  unsigned short* KVf = &KVs[0][0];

  // stage Q tile [256][64] through bufs 0-1 (32KB), swizzled
#pragma unroll
  for (int r = 0; r < 4; ++r) {
    int c = r * 512 + tid;       // 2048 chunks
    int row = c >> 3, cl = c & 7;
    int gc = cl ^ (row & 7);
    async16(Qh + (size_t)(q0 + row) * 64 + gc * 8, &KVf[c * 8]);
  }
  asm volatile("s_waitcnt vmcnt(0)" ::: "memory");
  __builtin_amdgcn_s_barrier();
  asm volatile("" ::: "memory");
  // Q B-frags (persist in regs): B[n=q][k=d], q = w*32 + nt*16 + mrow
  s16x8 qb[2][2];
#pragma unroll
  for (int nt = 0; nt < 2; ++nt)
#pragma unroll
    for (int ks = 0; ks < 2; ++ks) {
      int row = w * 32 + nt * 16 + mrow;
      qb[nt][ks] = *(const s16x8*)&KVf[row * 64 + (((ks * 4 + quad) ^ (row & 7)) << 3)];
    }
  asm volatile("" ::: "memory");
  __builtin_amdgcn_s_barrier();   // all waves done reading Q; bufs free
  asm volatile("" ::: "memory");

  // prologue: issue j=0 -> buf0, j=1 -> buf1 (2 async16/thread each)
  {
    int row = tid >> 3, cl = tid & 7, gc = cl ^ (row & 7);
    async16(Kh + (size_t)row * 64 + gc * 8, &KVs[0][tid * 8]);
    async16(Vh + (size_t)row * 2048 + gc * 8, &KVs[0][4096 + tid * 8]);
    async16(Kh + (size_t)(64 + row) * 64 + gc * 8, &KVs[1][tid * 8]);
    async16(Vh + (size_t)row * 2048 + 64 + gc * 8, &KVs[1][4096 + tid * 8]);
  }

  const f32x4 fz = {0.f, 0.f, 0.f, 0.f};
  f32x4 o[2][4];        // [q-tile][d-tile]
  float lr[2];          // per-lane partial row sums, q = nt*16 + (lane&15)
#pragma unroll
  for (int nt = 0; nt < 2; ++nt) {
    lr[nt] = 0.f;
#pragma unroll
    for (int dt = 0; dt < 4; ++dt) o[nt][dt] = fz;
  }

  for (int j = 0; j < 32; ++j) {
    // own loads(j) retired (leaves loads(j+1) = 2 outstanding)
    asm volatile("s_waitcnt vmcnt(2)" ::: "memory");
    __builtin_amdgcn_s_barrier();   // ALL waves' loads(j) landed; all reads of
                                    // buf (j-1)%3 == (j+2)%3 retired
    asm volatile("" ::: "memory");
    // issue prefetch j+2 into buf (j+2)%3 (wrap past end: harmless junk)
    {
      int jj = (j + 2) & 31;
      unsigned short* nb = &KVs[(j + 2) % 3][0];
      int row = tid >> 3, cl = tid & 7, gc = cl ^ (row & 7);
      async16(Kh + (size_t)(jj * 64 + row) * 64 + gc * 8, &nb[tid * 8]);
      async16(Vh + (size_t)row * 2048 + jj * 64 + gc * 8, &nb[4096 + tid * 8]);
    }
    const unsigned short* Kt = &KVs[j % 3][0];
    const unsigned short* Vs = &KVs[j % 3][4096];

    // software-pipelined compute: MFMA clusters adjacent to independent trans work
    AK a0 = load_ak(Kt, 0, mrow, quad); ST t0 = qkmm(a0, qb);
    AK a1 = load_ak(Kt, 1, mrow, quad); ST t1 = qkmm(a1, qb);
    PAT p0 = expp(t0, lr);
    AK a2 = load_ak(Kt, 2, mrow, quad); ST t2 = qkmm(a2, qb);
    pv(Vs, 0, p0, o, mrow, quad);
    PAT p1 = expp(t1, lr);
    AK a3 = load_ak(Kt, 3, mrow, quad); ST t3 = qkmm(a3, qb);
    pv(Vs, 1, p1, o, mrow, quad);
    PAT p2 = expp(t2, lr);
    pv(Vs, 2, p2, o, mrow, quad);
    PAT p3 = expp(t3, lr);
    pv(Vs, 3, p3, o, mrow, quad);
  }

  // reduce lr across the 4 quads (each lane then holds full sum for q = nt*16 + mrow)
#pragma unroll
  for (int nt = 0; nt < 2; ++nt) {
    float v = lr[nt];
    v += __shfl_xor(v, 16);
    v += __shfl_xor(v, 32);
    lr[nt] = v;
  }

  // normalize + write AO [B][L][H*D] bf16
  // o[nt][dt][i] is row q_local = quad*4+i of tile nt; col d = dt*16 + mrow
  int b_ = bh >> 4, h = bh & 15;
#pragma unroll
  for (int nt = 0; nt < 2; ++nt)
#pragma unroll
    for (int i = 0; i < 4; ++i) {
      float inv = 1.f / __shfl(lr[nt], quad * 4 + i, 64);
      int qrow = q0 + w * 32 + nt * 16 + quad * 4 + i;
#pragma unroll
      for (int dt = 0; dt < 4; ++dt) {
        int d = dt * 16 + mrow;
        AO[((size_t)(b_ * 2048 + qrow)) * 1024 + h * 64 + d] = f2bf(o[nt][dt][i] * inv);
      }
    }
}

// ---------------- GEMM2: out = AO @ WoT^T + bo (r7 proven, unchanged) ---------
__global__ __launch_bounds__(512) void k_gemm_out(
    const unsigned short* __restrict__ Ab, const unsigned short* __restrict__ WoT,
    const float* __restrict__ bo, float* __restrict__ out) {
  __shared__ __align__(16) unsigned short St[3][8192];  // [stage][A 128x32 | B 128x32]
  const int tid = threadIdx.x;
  const int w = tid >> 6, lane = tid & 63;
  const int quad = lane >> 4, mrow = lane & 15;
  const int lin = blockIdx.x + 64 * blockIdx.y;
  const int swz = (lin & 7) * 64 + (lin >> 3);   // 512 % 8 == 0 -> bijective
  const int m0 = (swz & 63) * 128, n0 = (swz >> 6) * 128;
  const int wr = (w >> 1) * 32, wc = (w & 1) * 64;   // wave = 32x64 out
  const unsigned short* PA = Ab + (size_t)m0 * 1024;
  const unsigned short* PB = WoT + (size_t)n0 * 1024;

  auto issue = [&](int kt, int s) {
    int ktw = kt & 31;
    {
      int c = tid;                      // A: 512 chunks
      int row = c >> 2, cl = c & 3, gc = cl ^ (row & 3);
      async16(PA + (size_t)row * 1024 + ktw * 32 + gc * 8, &St[s][c * 8]);
    }
    {
      int c = tid;                      // B: 512 chunks
      int row = c >> 2, cl = c & 3, gc = cl ^ (row & 3);
      async16(PB + (size_t)row * 1024 + ktw * 32 + gc * 8, &St[s][4096 + c * 8]);
    }
  };

  const f32x4 fz = {0.f, 0.f, 0.f, 0.f};
  f32x4 acc[2][4];
#pragma unroll
  for (int a = 0; a < 2; ++a)
#pragma unroll
    for (int b = 0; b < 4; ++b) acc[a][b] = fz;

  issue(0, 0);
  issue(1, 1);

  for (int kt = 0; kt < 32; ++kt) {
    asm volatile("s_waitcnt vmcnt(2)" ::: "memory");
    __builtin_amdgcn_s_barrier();
    asm volatile("" ::: "memory");
    issue(kt + 2, (kt + 2) % 3);
    const unsigned short* As = &St[kt % 3][0];
    const unsigned short* Bs = &St[kt % 3][4096];
    s16x8 a[2], b[4];
#pragma unroll
    for (int mt = 0; mt < 2; ++mt) {
      int row = wr + mt * 16 + mrow;
      a[mt] = *(const s16x8*)&As[row * 32 + ((quad ^ (row & 3)) << 3)];
    }
#pragma unroll
    for (int nt = 0; nt < 4; ++nt) {
      int row = wc + nt * 16 + mrow;
      b[nt] = *(const s16x8*)&Bs[row * 32 + ((quad ^ (row & 3)) << 3)];
    }
#pragma unroll
    for (int mt = 0; mt < 2; ++mt)
#pragma unroll
      for (int nt = 0; nt < 4; ++nt)
        acc[mt][nt] = __builtin_amdgcn_mfma_f32_16x16x32_bf16(a[mt], b[nt], acc[mt][nt], 0, 0, 0);
  }
#pragma unroll
  for (int mt = 0; mt < 2; ++mt)
#pragma unroll
    for (int nt = 0; nt < 4; ++nt)
#pragma unroll
      for (int i = 0; i < 4; ++i) {
        int row = m0 + wr + mt * 16 + quad * 4 + i;
        int col = n0 + wc + nt * 16 + mrow;
        out[(size_t)row * 1024 + col] = acc[mt][nt][i] + bo[col];
      }
}

extern "C" void kernel_launch(void* const* d_in, const int* in_sizes, int n_in,
                              void* d_out, int out_size, void* d_ws, size_t ws_size,
                              hipStream_t stream) {
  const float* x  = (const float*)d_in[0];
  const float* Wq = (const float*)d_in[1];
  const float* Wk = (const float*)d_in[2];
  const float* Wv = (const float*)d_in[3];
  const float* Wo = (const float*)d_in[4];
  const float* bo = (const float*)d_in[5];
  float* out = (float*)d_out;

  char* ws = (char*)d_ws;
  const size_t MiB = 1u << 20;
  unsigned short* xb  = (unsigned short*)(ws);              // 16 MiB, reused as AO
  unsigned short* Wt  = (unsigned short*)(ws + 16 * MiB);   // 6 MiB  (Wq^T|Wk^T|Wv^T)
  unsigned short* WoT = (unsigned short*)(ws + 22 * MiB);   // 2 MiB
  unsigned short* Qb  = (unsigned short*)(ws + 24 * MiB);   // 16 MiB [B,H,L,D]
  unsigned short* Kb  = (unsigned short*)(ws + 40 * MiB);   // 16 MiB [B,H,L,D] (pre-scaled)
  unsigned short* Vt  = (unsigned short*)(ws + 56 * MiB);   // 16 MiB [B,H,D,L]
  unsigned short* AO  = xb;  // x/xb no longer needed after the merged GEMM

  k_prep<<<12288, 256, 0, stream>>>(x, Wq, Wk, Wv, Wo, xb, Wt, WoT);
  k_gemm_qkvt<<<768, 512, 0, stream>>>(xb, Wt, Qb, Kb, Vt);
  k_attn<<<dim3(8, 64), 512, 0, stream>>>(Qb, Kb, Vt, AO);
  k_gemm_out<<<dim3(64, 8), 512, 0, stream>>>(AO, WoT, bo, out);
}